// Round 9
// baseline (860.852 us; speedup 1.0000x reference)
//
#include <hip/hip_runtime.h>

#define T_STEPS 336
#define NWG 32
#define NREP 4

typedef unsigned long long u64;

// Device-global scratch. Replica slot tags are re-initialized by their OWNING
// WG at lstm startup each call (first call: .bss zeros = tag0|h0=0, exactly
// the valid t=0 state; later calls: stale tags 336/335 never match 0/1).
// 4 replicas x 2 parities x 8 wave-windows x 64 slots: (tag<<32)|h_bits.
// Consumer WG r polls replica r&3 -> 8 waves per 512B window (round-5
// confirmed optimum; NREP=8/striding null in r7; r4/r6: pipelined polls
// structurally regress; r1-3: sc-bit games never transport).
__device__ u64 g_rep[NREP][2][8][64];

__device__ __forceinline__ float softplus_f(float x) {
  return (x > 20.f) ? x : log1pf(__expf(x));
}
__device__ __forceinline__ float sigmoid_f(float x) {
  return 1.f / (1.f + __expf(-x));
}
__device__ __forceinline__ float tanh_f(float x) {
  x = fminf(fmaxf(x, -15.f), 15.f);
  float e = __expf(-2.f * x);
  return (1.f - e) / (1.f + e);
}

// ---------------- persistent LSTM recurrence + FUSED head ----------------
// Recurrence: EXACT round-5 structure (best proven: 574us, zero outliers):
// 32 WGs x 512 threads, relaxed agent-atomic publish to 4 replicas, plain
// single-outstanding atomic-load polling, parity double-buffer, one
// barrier/step. WG r owns h-indices [16r,16r+16). Thread (seg=tid>>6,
// cl=tid&63): col=(cl>>4)*512+16r+(cl&15), rows [64seg,64seg+64), 64 sampled
// Whh weights in registers. Wave seg polls exactly the 64 h-slots its dot
// consumes -> no poll->dot barrier.
//
// FUSION (round-8 lesson: the constant 113-115us total-lstm gap is layout-
// independent — second-launch overhead + every head input line being a
// dirty-in-remote-L2 MALL miss; both die with the second kernel):
//  * Head row j needs h_{81+j}. At iteration t, hs[] holds the FULL h_t in
//    every WG -> WG r (rows 8r..8r+7) captures hs into head_h[] LDS at its 8
//    owned steps (predicated reg->LDS store, scalar-uniform condition, off
//    the critical path). Row 255 needs h_336 (published at end of t=335,
//    never consumed in-loop): WG 31 does ONE extra proven poll of tag 336.
//    Acyclic: that poll depends only on publishes preceding loop exit.
//  * BLW is sampled ON THE FLY from blw_mu/rho/eps (read-only params ->
//    always coherent, L1/L2-cacheable; per-thread-contiguous addresses).
//    No g_blwT staging, no intra-kernel coherence machinery needed.
//  * g_h / g_blwT / head_kernel / second launch: deleted.
__global__ __launch_bounds__(512) void lstm_kernel(
    const float* __restrict__ x, const float* __restrict__ drop_x,
    const float* __restrict__ wih_mu, const float* __restrict__ wih_rho, const float* __restrict__ eps_wih,
    const float* __restrict__ b_mu, const float* __restrict__ b_rho, const float* __restrict__ eps_b,
    const float* __restrict__ whh_mu, const float* __restrict__ whh_rho, const float* __restrict__ eps_whh,
    const float* __restrict__ blw_mu, const float* __restrict__ blw_rho, const float* __restrict__ eps_blw,
    const float* __restrict__ drop_h, const float* __restrict__ drop_l,
    const float* __restrict__ blb_mu, const float* __restrict__ blb_rho, const float* __restrict__ eps_blb,
    const float* __restrict__ lin_w, float* __restrict__ out)
{
  const int r = blockIdx.x;         // 0..31
  const int tid = threadIdx.x;      // 0..511
  const int cl = tid & 63;
  const int seg = tid >> 6;         // 0..7
  const int gate = cl >> 4, kl = cl & 15;
  const int col = gate * 512 + r * 16 + kl;
  const int row0 = seg * 64;
  const int rep = r & (NREP - 1);   // my WG's poll replica

  // FIRST: re-tag my own 16 slots for t=0 (all replicas, both parities).
  // Owners-only -> no cross-WG write races; consumers' t=0 polls wait for
  // these stores (or hit first-launch .bss zeros = valid t=0 state).
  if (tid < 16) {
    const int idx = r * 16 + tid;
    const int sw = idx >> 6, sc = idx & 63;
    #pragma unroll
    for (int q = 0; q < NREP; ++q) {
      __hip_atomic_store(&g_rep[q][0][sw][sc], 0ULL, __ATOMIC_RELAXED, __HIP_MEMORY_SCOPE_AGENT);
      __hip_atomic_store(&g_rep[q][1][sw][sc], 0ULL, __ATOMIC_RELAXED, __HIP_MEMORY_SCOPE_AGENT);
    }
  }

  __shared__ float xd[336 * 16];      // x*drop_x for batch 255 (21.0 KB)
  __shared__ float hs[512];           // fp32 h copy (2 KB)
  __shared__ float part[2][8][64];    // parity-double-buffered partials (4 KB)
  __shared__ float head_h[8][512];    // captured h_{81+8r+jj} rows (16 KB)
  __shared__ float party[2][8][256];  // head partial dots / y rows (16 KB)
  // total LDS ~59.4 KB (< 64 KB static limit; 32 blocks -> occupancy moot)

  for (int e = tid; e < 5376; e += 512) {
    const int src = 255 * 5376 + e;   // batch-255 slice is contiguous
    xd[e] = x[src] * drop_x[src];
  }

  // 64 sampled Whh weights into registers.
  float w[64];
  #pragma unroll
  for (int j = 0; j < 64; ++j) {
    const int idx = (row0 + j) * 2048 + col;
    w[j] = whh_mu[idx] + softplus_f(whh_rho[idx]) * eps_whh[idx];
  }

  // Wave 0: Wih column + bias for on-the-fly xg.
  float wih[16];
  float bias = 0.f;
  if (tid < 64) {
    bias = b_mu[col] + softplus_f(b_rho[col]) * eps_b[col];
    #pragma unroll
    for (int i = 0; i < 16; ++i) {
      const int idx = i * 2048 + col;
      wih[i] = wih_mu[idx] + softplus_f(wih_rho[idx]) * eps_wih[idx];
    }
  }
  __syncthreads();                  // xd staged

  auto xg_at = [&](int t) -> float {
    const float4* xr = (const float4*)(xd + t * 16);
    float4 x0 = xr[0], x1 = xr[1], x2 = xr[2], x3 = xr[3];
    float s0 = fmaf(x0.x, wih[0], bias);
    s0 = fmaf(x0.y, wih[1], s0); s0 = fmaf(x0.z, wih[2], s0); s0 = fmaf(x0.w, wih[3], s0);
    float s1 = x1.x * wih[4];
    s1 = fmaf(x1.y, wih[5], s1); s1 = fmaf(x1.z, wih[6], s1); s1 = fmaf(x1.w, wih[7], s1);
    float s2 = x2.x * wih[8];
    s2 = fmaf(x2.y, wih[9], s2); s2 = fmaf(x2.z, wih[10], s2); s2 = fmaf(x2.w, wih[11], s2);
    float s3 = x3.x * wih[12];
    s3 = fmaf(x3.y, wih[13], s3); s3 = fmaf(x3.z, wih[14], s3); s3 = fmaf(x3.w, wih[15], s3);
    return (s0 + s1) + (s2 + s3);
  };

  float c = 0.f;                    // cell state (wave-0 lanes 0..15)
  float xgv = (tid < 64) ? xg_at(0) : 0.f;

  for (int t = 0; t < T_STEPS; ++t) {
    const int p = t & 1;

    // Poll my replica slot (proven transport, baseline rate; tag t carries
    // the h value). Only 8 waves poll this 512B window -> short MALL queues.
    {
      const u64* slot = &g_rep[rep][p][seg][cl];
      u64 v;
      int it = 0;
      for (;;) {
        v = __hip_atomic_load(slot, __ATOMIC_RELAXED, __HIP_MEMORY_SCOPE_AGENT);
        if ((unsigned)(v >> 32) == (unsigned)t) break;
        if (++it > (1 << 22)) break;   // anti-hang insurance (never fires in practice)
      }
      hs[tid] = __uint_as_float((unsigned)v);
      // Head capture: WG r owns rows j=8r..8r+7 = h_{81+8r..88+8r}; hs at
      // iteration t IS h_t. Scalar-uniform condition, reg->LDS store only.
      if (t >= 81 && ((t - 81) >> 3) == r)
        head_h[(t - 81) & 7][tid] = __uint_as_float((unsigned)v);
    }
    // No barrier: wave seg's dot reads hs[row0..row0+64) = its own lanes' data.

    float a0 = 0.f, a1 = 0.f, a2 = 0.f, a3 = 0.f;
    const float4* hv = (const float4*)(hs + row0);
    #pragma unroll
    for (int jj = 0; jj < 16; ++jj) {
      float4 h4 = hv[jj];
      a0 = fmaf(h4.x, w[4 * jj],     a0);
      a1 = fmaf(h4.y, w[4 * jj + 1], a1);
      a2 = fmaf(h4.z, w[4 * jj + 2], a2);
      a3 = fmaf(h4.w, w[4 * jj + 3], a3);
    }
    part[p][seg][cl] = (a0 + a1) + (a2 + a3);
    __syncthreads();   // single rendezvous per step (skew-safe via parity bufs)

    if (tid < 64) {
      float g = xgv
              + ((part[p][0][tid] + part[p][1][tid]) + (part[p][2][tid] + part[p][3][tid]))
              + ((part[p][4][tid] + part[p][5][tid]) + (part[p][6][tid] + part[p][7][tid]));
      // Parallel activation on all 64 lanes (one exp chain each):
      // gates i,f,o -> sigmoid; gate g -> tanh = 2*sigmoid(2x)-1 (clamped).
      const bool is_g = (gate == 2);
      float xin = is_g ? 2.f * fminf(fmaxf(g, -15.f), 15.f) : g;
      float s = sigmoid_f(xin);
      float act = is_g ? 2.f * s - 1.f : s;
      float vi = __shfl(act, kl);
      float vf = __shfl(act, kl + 16);
      float vg = __shfl(act, kl + 32);
      float vo = __shfl(act, kl + 48);
      if (tid < 16) {
        c = vf * c + vi * vg;
        float h = vo * tanh_f(c);
        const int idx = r * 16 + tid;
        const int sw = idx >> 6, sc = idx & 63;
        u64 pv = (((u64)(unsigned)(t + 1)) << 32) | (u64)__float_as_uint(h);
        // Publish to all 4 replicas (fire-and-forget; acks retire under the
        // next step's poll wait, proven free in round 5).
        #pragma unroll
        for (int q = 0; q < NREP; ++q)
          __hip_atomic_store(&g_rep[q][(t + 1) & 1][sw][sc], pv,
                             __ATOMIC_RELAXED, __HIP_MEMORY_SCOPE_AGENT);
      }
      if (t + 1 < T_STEPS) xgv = xg_at(t + 1);         // off critical path
    }
  }

  // ================= fused head (post-loop, per-WG independent) =========
  // Row 255 = h_336: published at end of t=335 but never consumed in-loop.
  // WG 31 polls tag 336 (parity 0) — the proven primitive; depends only on
  // publishes that precede every WG's loop exit (acyclic, no deadlock).
  if (r == 31) {
    const u64* slot = &g_rep[rep][0][seg][cl];
    u64 v;
    int it = 0;
    for (;;) {
      v = __hip_atomic_load(slot, __ATOMIC_RELAXED, __HIP_MEMORY_SCOPE_AGENT);
      if ((unsigned)(v >> 32) == 336u) break;
      if (++it > (1 << 22)) break;   // anti-hang insurance
    }
    head_h[7][tid] = __uint_as_float((unsigned)v);
  }

  // Scale by drop_h: thread tid touches ONLY its own captured slots
  // head_h[jj][tid] (no cross-thread reads -> no barrier needed before).
  #pragma unroll
  for (int jj = 0; jj < 8; ++jj)
    head_h[jj][tid] *= drop_h[(r * 8 + jj) * 512 + tid];
  __syncthreads();   // head_h complete & scaled for the whole WG

  // y[j][l] = relu( sum_k hd[j][k]*BLW[l][k] + BLb[l] ) * drop_l[j][l]
  // Thread (l=tid&255, kh=tid>>8) accumulates its k-half for all 8 rows,
  // sampling BLW[l][k] on the fly (per-thread contiguous param reads,
  // L1-cached across the unroll; head_h[jj][k] is a lane-uniform LDS
  // broadcast). One softplus per (k,l), amortized over 8 rows.
  {
    const int l = tid & 255;
    const int kh = tid >> 8;
    const int kbase = kh * 256;
    float acc[8] = {0.f, 0.f, 0.f, 0.f, 0.f, 0.f, 0.f, 0.f};
    const float* mu  = blw_mu  + l * 512 + kbase;
    const float* rho = blw_rho + l * 512 + kbase;
    const float* ep  = eps_blw + l * 512 + kbase;
    #pragma unroll 8
    for (int kk = 0; kk < 256; ++kk) {
      const float wv = mu[kk] + softplus_f(rho[kk]) * ep[kk];
      const int k = kbase + kk;
      #pragma unroll
      for (int jj = 0; jj < 8; ++jj)
        acc[jj] = fmaf(head_h[jj][k], wv, acc[jj]);
    }
    #pragma unroll
    for (int jj = 0; jj < 8; ++jj) party[kh][jj][l] = acc[jj];
  }
  __syncthreads();

  // Combine halves, add sampled bias, ReLU, drop_l. Overwrite party[0] as y.
  if (tid < 256) {
    const int l = tid;
    const float b = blb_mu[l] + softplus_f(blb_rho[l]) * eps_blb[l];
    #pragma unroll
    for (int jj = 0; jj < 8; ++jj) {
      const int j = r * 8 + jj;
      float yv = fmaxf(party[0][jj][l] + party[1][jj][l] + b, 0.f);
      party[0][jj][l] = yv * drop_l[j * 256 + l];
    }
  }
  __syncthreads();

  // out[j][o] = y[j] . lin_w[o]  (80 threads: jj=tid/10, o=tid%10)
  if (tid < 80) {
    const int jj = tid / 10, o = tid - jj * 10;
    const float* lrow = lin_w + o * 256;
    const float* yrow = party[0][jj];
    float acc = 0.f;
    #pragma unroll 8
    for (int l2 = 0; l2 < 256; ++l2) acc = fmaf(yrow[l2], lrow[l2], acc);
    out[(r * 8 + jj) * 10 + o] = acc;
  }
}

// ---------------- launch (ONE dispatch) ----------------
extern "C" void kernel_launch(void* const* d_in, const int* in_sizes, int n_in,
                              void* d_out, int out_size, void* d_ws, size_t ws_size,
                              hipStream_t stream) {
  const float* x        = (const float*)d_in[0];
  const float* drop_x   = (const float*)d_in[1];
  const float* drop_h   = (const float*)d_in[2];
  const float* drop_l   = (const float*)d_in[3];
  const float* wih_mu   = (const float*)d_in[4];
  const float* wih_rho  = (const float*)d_in[5];
  const float* eps_wih  = (const float*)d_in[6];
  const float* whh_mu   = (const float*)d_in[7];
  const float* whh_rho  = (const float*)d_in[8];
  const float* eps_whh  = (const float*)d_in[9];
  const float* b_mu     = (const float*)d_in[10];
  const float* b_rho    = (const float*)d_in[11];
  const float* eps_b    = (const float*)d_in[12];
  const float* blw_mu   = (const float*)d_in[13];
  const float* blw_rho  = (const float*)d_in[14];
  const float* eps_blw  = (const float*)d_in[15];
  const float* blb_mu   = (const float*)d_in[16];
  const float* blb_rho  = (const float*)d_in[17];
  const float* eps_blb  = (const float*)d_in[18];
  const float* lin_w    = (const float*)d_in[19];

  lstm_kernel<<<NWG, 512, 0, stream>>>(x, drop_x,
                                       wih_mu, wih_rho, eps_wih,
                                       b_mu, b_rho, eps_b,
                                       whh_mu, whh_rho, eps_whh,
                                       blw_mu, blw_rho, eps_blw,
                                       drop_h, drop_l,
                                       blb_mu, blb_rho, eps_blb,
                                       lin_w, (float*)d_out);
}

// Round 10
// 693.412 us; speedup vs baseline: 1.2415x; 1.2415x over previous
//
#include <hip/hip_runtime.h>

#define T_STEPS 336
#define NWG 32
#define NREP 4

typedef unsigned long long u64;

// Device-global scratch. Replica slot tags are re-initialized by their OWNING
// WG at lstm startup each call (first call: .bss zeros = tag0|h0=0, exactly
// the valid t=0 state; later calls: stale tags 336/335 never match 0/1).
__device__ float g_h[337 * 512];      // h_1..h_336 (head reads t>=81)
__device__ float g_blwT[512 * 256];   // sampled BayesianLinear weight, TRANSPOSED [k][l]
// 4 replicas x 2 parities x 8 wave-windows x 64 slots: (tag<<32)|h_bits.
// Replication divides per-line poll contention by 4: consumer WG r polls
// replica r&3, so each 512B window is polled by 8 waves instead of 32.
//
// FINAL LEDGER (rounds 0-9): this is the measured floor structure.
//  - per-step 1.71us = MALL store-visibility + poll-discovery RT (latency-
//    bound: VALUBusy ~3%, HBM ~0.7% — no pipe loaded).
//  - sc0/sc1 cache-bit transport: never works, even XCC_ID-verified
//    same-XCD (r1-3). Relaxed agent atomics are the ONLY transport.
//  - pipelined vmcnt(N) polling: structural regression, refuted twice
//    (r4 +0.34us/step, r6 +0.30us/step) — pre-barrier drain costs ~RT.
//  - NREP=4 replication: the one collected win (r5, -45us).
//  - NREP=8 / 4KB channel striding: null (r7) — contention axis exhausted.
//  - head access-pattern fix (this file): kernel-side null; head is ~10us.
//  - fusing head into lstm: NEGATIVE (r9, +180us param-gather) and proved
//    the ~105us total-vs-kernel gap is harness-fixed (persists at 1 dispatch).
__device__ u64   g_rep[NREP][2][8][64];

__device__ __forceinline__ float softplus_f(float x) {
  return (x > 20.f) ? x : log1pf(__expf(x));
}
__device__ __forceinline__ float sigmoid_f(float x) {
  return 1.f / (1.f + __expf(-x));
}
__device__ __forceinline__ float tanh_f(float x) {
  x = fminf(fmaxf(x, -15.f), 15.f);
  float e = __expf(-2.f * x);
  return (1.f - e) / (1.f + e);
}

// ---------------- persistent LSTM recurrence ----------------
// EXACT round-5 recurrence (best proven: 574us, zero outliers): 32 WGs x 512
// threads, relaxed agent-atomic publish to 4 replicas, plain single-
// outstanding atomic-load polling, parity double-buffer, one barrier/step.
// WG r owns h-indices [16r,16r+16). Thread (seg=tid>>6, cl=tid&63):
// col=(cl>>4)*512+16r+(cl&15), rows [64seg,64seg+64), 64 sampled Whh weights
// in registers (FULL unroll or w[] demotes to scratch). Wave seg polls exactly
// the 64 h-slots its dot consumes -> no poll->dot barrier; part[] parity-
// double-buffered -> single __syncthreads per step.
// BLW is sampled TRANSPOSED (WT[k][l]) so the head's inner loop is coalesced.
__global__ __launch_bounds__(512) void lstm_kernel(
    const float* __restrict__ x, const float* __restrict__ drop_x,
    const float* __restrict__ wih_mu, const float* __restrict__ wih_rho, const float* __restrict__ eps_wih,
    const float* __restrict__ b_mu, const float* __restrict__ b_rho, const float* __restrict__ eps_b,
    const float* __restrict__ whh_mu, const float* __restrict__ whh_rho, const float* __restrict__ eps_whh,
    const float* __restrict__ blw_mu, const float* __restrict__ blw_rho, const float* __restrict__ eps_blw)
{
  const int r = blockIdx.x;         // 0..31
  const int tid = threadIdx.x;      // 0..511
  const int cl = tid & 63;
  const int seg = tid >> 6;         // 0..7
  const int gate = cl >> 4, kl = cl & 15;
  const int col = gate * 512 + r * 16 + kl;
  const int row0 = seg * 64;
  const int rep = r & (NREP - 1);   // my WG's poll replica

  // FIRST: re-tag my own 16 slots for t=0 (all replicas, both parities).
  // Owners-only -> no cross-WG write races; consumers' t=0 polls wait for
  // these stores (or hit first-launch .bss zeros = valid t=0 state).
  if (tid < 16) {
    const int idx = r * 16 + tid;
    const int sw = idx >> 6, sc = idx & 63;
    #pragma unroll
    for (int q = 0; q < NREP; ++q) {
      __hip_atomic_store(&g_rep[q][0][sw][sc], 0ULL, __ATOMIC_RELAXED, __HIP_MEMORY_SCOPE_AGENT);
      __hip_atomic_store(&g_rep[q][1][sw][sc], 0ULL, __ATOMIC_RELAXED, __HIP_MEMORY_SCOPE_AGENT);
    }
  }

  __shared__ float xd[336 * 16];    // x*drop_x for batch 255
  __shared__ float hs[512];         // fp32 h copy (wave-local segments)
  __shared__ float part[2][8][64];  // parity-double-buffered partials

  // One-time: sample BLW, stored TRANSPOSED for the head's coalesced read.
  // Reads contiguous (e = l*512+k, consecutive); writes scatter (stride-1KB),
  // fire-and-forget, hidden under startup.
  {
    const int e0 = (r * 512 + tid) * 8;
    #pragma unroll
    for (int q = 0; q < 8; ++q) {
      const int e = e0 + q;                 // e = l*512 + k
      const float wv = blw_mu[e] + softplus_f(blw_rho[e]) * eps_blw[e];
      g_blwT[(e & 511) * 256 + (e >> 9)] = wv;   // WT[k][l]
    }
  }

  for (int e = tid; e < 5376; e += 512) {
    const int src = 255 * 5376 + e;   // batch-255 slice is contiguous
    xd[e] = x[src] * drop_x[src];
  }

  // 64 sampled Whh weights into registers.
  float w[64];
  #pragma unroll
  for (int j = 0; j < 64; ++j) {
    const int idx = (row0 + j) * 2048 + col;
    w[j] = whh_mu[idx] + softplus_f(whh_rho[idx]) * eps_whh[idx];
  }

  // Wave 0: Wih column + bias for on-the-fly xg.
  float wih[16];
  float bias = 0.f;
  if (tid < 64) {
    bias = b_mu[col] + softplus_f(b_rho[col]) * eps_b[col];
    #pragma unroll
    for (int i = 0; i < 16; ++i) {
      const int idx = i * 2048 + col;
      wih[i] = wih_mu[idx] + softplus_f(wih_rho[idx]) * eps_wih[idx];
    }
  }
  __syncthreads();                  // xd staged

  auto xg_at = [&](int t) -> float {
    const float4* xr = (const float4*)(xd + t * 16);
    float4 x0 = xr[0], x1 = xr[1], x2 = xr[2], x3 = xr[3];
    float s0 = fmaf(x0.x, wih[0], bias);
    s0 = fmaf(x0.y, wih[1], s0); s0 = fmaf(x0.z, wih[2], s0); s0 = fmaf(x0.w, wih[3], s0);
    float s1 = x1.x * wih[4];
    s1 = fmaf(x1.y, wih[5], s1); s1 = fmaf(x1.z, wih[6], s1); s1 = fmaf(x1.w, wih[7], s1);
    float s2 = x2.x * wih[8];
    s2 = fmaf(x2.y, wih[9], s2); s2 = fmaf(x2.z, wih[10], s2); s2 = fmaf(x2.w, wih[11], s2);
    float s3 = x3.x * wih[12];
    s3 = fmaf(x3.y, wih[13], s3); s3 = fmaf(x3.z, wih[14], s3); s3 = fmaf(x3.w, wih[15], s3);
    return (s0 + s1) + (s2 + s3);
  };

  float c = 0.f;                    // cell state (wave-0 lanes 0..15)
  float xgv = (tid < 64) ? xg_at(0) : 0.f;

  for (int t = 0; t < T_STEPS; ++t) {
    const int p = t & 1;

    // Poll my replica slot (proven transport, baseline rate; tag t carries
    // the h value). Only 8 waves poll this 512B window -> short MALL queues.
    {
      const u64* slot = &g_rep[rep][p][seg][cl];
      u64 v;
      int it = 0;
      for (;;) {
        v = __hip_atomic_load(slot, __ATOMIC_RELAXED, __HIP_MEMORY_SCOPE_AGENT);
        if ((unsigned)(v >> 32) == (unsigned)t) break;
        if (++it > (1 << 22)) break;   // anti-hang insurance (never fires in practice)
      }
      hs[tid] = __uint_as_float((unsigned)v);
    }
    // No barrier: wave seg's dot reads hs[row0..row0+64) = its own lanes' data.

    float a0 = 0.f, a1 = 0.f, a2 = 0.f, a3 = 0.f;
    const float4* hv = (const float4*)(hs + row0);
    #pragma unroll
    for (int jj = 0; jj < 16; ++jj) {
      float4 h4 = hv[jj];
      a0 = fmaf(h4.x, w[4 * jj],     a0);
      a1 = fmaf(h4.y, w[4 * jj + 1], a1);
      a2 = fmaf(h4.z, w[4 * jj + 2], a2);
      a3 = fmaf(h4.w, w[4 * jj + 3], a3);
    }
    part[p][seg][cl] = (a0 + a1) + (a2 + a3);
    __syncthreads();   // single rendezvous per step (skew-safe via parity bufs)

    if (tid < 64) {
      float g = xgv
              + ((part[p][0][tid] + part[p][1][tid]) + (part[p][2][tid] + part[p][3][tid]))
              + ((part[p][4][tid] + part[p][5][tid]) + (part[p][6][tid] + part[p][7][tid]));
      // Parallel activation on all 64 lanes (one exp chain each):
      // gates i,f,o -> sigmoid; gate g -> tanh = 2*sigmoid(2x)-1 (clamped).
      const bool is_g = (gate == 2);
      float xin = is_g ? 2.f * fminf(fmaxf(g, -15.f), 15.f) : g;
      float s = sigmoid_f(xin);
      float act = is_g ? 2.f * s - 1.f : s;
      float vi = __shfl(act, kl);
      float vf = __shfl(act, kl + 16);
      float vg = __shfl(act, kl + 32);
      float vo = __shfl(act, kl + 48);
      if (tid < 16) {
        c = vf * c + vi * vg;
        float h = vo * tanh_f(c);
        const int idx = r * 16 + tid;
        const int sw = idx >> 6, sc = idx & 63;
        u64 pv = (((u64)(unsigned)(t + 1)) << 32) | (u64)__float_as_uint(h);
        // Publish to all 4 replicas (fire-and-forget; acks retire under the
        // next step's poll wait, same as the baseline's single store).
        #pragma unroll
        for (int q = 0; q < NREP; ++q)
          __hip_atomic_store(&g_rep[q][(t + 1) & 1][sw][sc], pv,
                             __ATOMIC_RELAXED, __HIP_MEMORY_SCOPE_AGENT);
        g_h[(t + 1) * 512 + idx] = h;                  // for head (kernel-end flush)
      }
      if (t + 1 < T_STEPS) xgv = xg_at(t + 1);         // off critical path
    }
  }
}

// ---------------- head ----------------
// block j: last[j] = g_h[81+j]  (reshape(T,B,H)[-1] => h_{t=80+j} of batch 255)
// y[l] = relu(last*drop_h[j] . BLW[l] + BLb[l]) * drop_l[j,l]; out = y @ lin_w^T.
// BLW is stored transposed (WT[k][l]) by the lstm kernel, so the inner loop
// is COALESCED: at fixed k, lanes l read consecutive addresses.
// BLb sampled inline per block (256 redundant softplus -- free).
__global__ __launch_bounds__(256) void head_kernel(
    const float* __restrict__ drop_h, const float* __restrict__ drop_l,
    const float* __restrict__ blb_mu, const float* __restrict__ blb_rho,
    const float* __restrict__ eps_blb,
    const float* __restrict__ lin_w, float* __restrict__ out)
{
  const int j = blockIdx.x, tid = threadIdx.x;
  __shared__ float hd[512];
  __shared__ float y[256];

  for (int k = tid; k < 512; k += 256)
    hd[k] = g_h[(81 + j) * 512 + k] * drop_h[j * 512 + k];
  __syncthreads();

  {
    const int l = tid;
    float acc = blb_mu[l] + softplus_f(blb_rho[l]) * eps_blb[l];
    #pragma unroll 8
    for (int k = 0; k < 512; ++k)
      acc = fmaf(hd[k], g_blwT[k * 256 + l], acc);   // coalesced across lanes
    acc = fmaxf(acc, 0.f);
    y[l] = acc * drop_l[j * 256 + l];
  }
  __syncthreads();

  if (tid < 10) {
    float acc = 0.f;
    const float* lrow = lin_w + tid * 256;
    #pragma unroll 8
    for (int l = 0; l < 256; ++l) acc = fmaf(y[l], lrow[l], acc);
    out[j * 10 + tid] = acc;
  }
}

// ---------------- launch (2 dispatches) ----------------
extern "C" void kernel_launch(void* const* d_in, const int* in_sizes, int n_in,
                              void* d_out, int out_size, void* d_ws, size_t ws_size,
                              hipStream_t stream) {
  const float* x        = (const float*)d_in[0];
  const float* drop_x   = (const float*)d_in[1];
  const float* drop_h   = (const float*)d_in[2];
  const float* drop_l   = (const float*)d_in[3];
  const float* wih_mu   = (const float*)d_in[4];
  const float* wih_rho  = (const float*)d_in[5];
  const float* eps_wih  = (const float*)d_in[6];
  const float* whh_mu   = (const float*)d_in[7];
  const float* whh_rho  = (const float*)d_in[8];
  const float* eps_whh  = (const float*)d_in[9];
  const float* b_mu     = (const float*)d_in[10];
  const float* b_rho    = (const float*)d_in[11];
  const float* eps_b    = (const float*)d_in[12];
  const float* blw_mu   = (const float*)d_in[13];
  const float* blw_rho  = (const float*)d_in[14];
  const float* eps_blw  = (const float*)d_in[15];
  const float* blb_mu   = (const float*)d_in[16];
  const float* blb_rho  = (const float*)d_in[17];
  const float* eps_blb  = (const float*)d_in[18];
  const float* lin_w    = (const float*)d_in[19];

  lstm_kernel<<<NWG, 512, 0, stream>>>(x, drop_x,
                                       wih_mu, wih_rho, eps_wih,
                                       b_mu, b_rho, eps_b,
                                       whh_mu, whh_rho, eps_whh,
                                       blw_mu, blw_rho, eps_blw);

  head_kernel<<<256, 256, 0, stream>>>(drop_h, drop_l,
                                       blb_mu, blb_rho, eps_blb,
                                       lin_w, (float*)d_out);
}